// Round 1
// baseline (792.588 us; speedup 1.0000x reference)
//
#include <hip/hip_runtime.h>

#define EMB 32
#define SCAN_CHUNK 1024

// ---------------- CSR build ----------------

__global__ void hist_kernel(const int* __restrict__ rows, int nnz, int* __restrict__ cnt) {
    int stride = gridDim.x * blockDim.x;
    for (int i = blockIdx.x * blockDim.x + threadIdx.x; i < nnz; i += stride)
        atomicAdd(&cnt[rows[i]], 1);
}

// Exclusive scan, stage 1: per-block (1024 elems) scan in place, block totals out.
__global__ void scan_block_kernel(int* __restrict__ cnt, int n, int* __restrict__ blksum) {
    __shared__ int lds[256];
    const int t = threadIdx.x;
    const int idx = blockIdx.x * SCAN_CHUNK + t * 4;
    int4 v = make_int4(0, 0, 0, 0);
    if (idx + 3 < n) {
        v = *reinterpret_cast<const int4*>(cnt + idx);
    } else if (idx < n) {
        v.x = cnt[idx];
        if (idx + 1 < n) v.y = cnt[idx + 1];
        if (idx + 2 < n) v.z = cnt[idx + 2];
    }
    int s = v.x + v.y + v.z + v.w;
    lds[t] = s;
    __syncthreads();
    for (int off = 1; off < 256; off <<= 1) {
        int add = (t >= off) ? lds[t - off] : 0;
        __syncthreads();
        lds[t] += add;
        __syncthreads();
    }
    int incl = lds[t];
    int excl = incl - s;
    if (t == 255) blksum[blockIdx.x] = incl;
    int e0 = excl, e1 = e0 + v.x, e2 = e1 + v.y, e3 = e2 + v.z;
    if (idx + 3 < n) {
        *reinterpret_cast<int4*>(cnt + idx) = make_int4(e0, e1, e2, e3);
    } else if (idx < n) {
        cnt[idx] = e0;
        if (idx + 1 < n) cnt[idx + 1] = e1;
        if (idx + 2 < n) cnt[idx + 2] = e2;
    }
}

// Stage 2: exclusive scan of block totals (nblk <= 256).
__global__ void scan_tops_kernel(int* __restrict__ blksum, int nblk) {
    __shared__ int lds[256];
    int t = threadIdx.x;
    int s = (t < nblk) ? blksum[t] : 0;
    lds[t] = s;
    __syncthreads();
    for (int off = 1; off < 256; off <<= 1) {
        int add = (t >= off) ? lds[t - off] : 0;
        __syncthreads();
        lds[t] += add;
        __syncthreads();
    }
    if (t < nblk) blksum[t] = lds[t] - s;
}

// Stage 3: add block offsets -> row_ptr, and init scatter cursors (in cnt).
__global__ void scan_add_kernel(int* __restrict__ cnt, const int* __restrict__ blksum,
                                int n, int nnz, int* __restrict__ row_ptr) {
    int i = blockIdx.x * blockDim.x + threadIdx.x;
    if (i < n) {
        int v = cnt[i] + blksum[i / SCAN_CHUNK];
        row_ptr[i] = v;
        cnt[i] = v;  // running cursor for scatter
    } else if (i == n) {
        row_ptr[n] = nnz;
    }
}

__global__ void scatter_kernel(const float* __restrict__ vals, const int* __restrict__ rows,
                               const int* __restrict__ cols, int nnz,
                               int* __restrict__ cursor, int2* __restrict__ pairs) {
    int stride = gridDim.x * blockDim.x;
    for (int i = blockIdx.x * blockDim.x + threadIdx.x; i < nnz; i += stride) {
        int r = rows[i];
        int pos = atomicAdd(&cursor[r], 1);
        int2 p;
        p.x = __float_as_int(vals[i]);
        p.y = cols[i];
        pairs[pos] = p;
    }
}

// ---------------- misc ----------------

__global__ void softmax4_kernel(const float* __restrict__ alpha, float* __restrict__ coefs) {
    if (threadIdx.x == 0 && blockIdx.x == 0) {
        float m = fmaxf(fmaxf(alpha[0], alpha[1]), fmaxf(alpha[2], alpha[3]));
        float e0 = __expf(alpha[0] - m), e1 = __expf(alpha[1] - m);
        float e2 = __expf(alpha[2] - m), e3 = __expf(alpha[3] - m);
        float inv = 1.0f / (e0 + e1 + e2 + e3);
        coefs[0] = e0 * inv; coefs[1] = e1 * inv; coefs[2] = e2 * inv; coefs[3] = e3 * inv;
    }
}

// ---------------- CSR SpMM with fused weighted accumulation ----------------
// 8 lanes per row, float4 of EMB per lane. No atomics.

template <bool INIT, bool STORE_E>
__global__ void spmm_kernel(const int* __restrict__ row_ptr, const int2* __restrict__ pairs,
                            const float* __restrict__ X, float* __restrict__ Eout,
                            float* __restrict__ Efin, const float* __restrict__ coefs,
                            int hop, int n) {
    int tid = blockIdx.x * blockDim.x + threadIdx.x;
    int row = tid >> 3;
    if (row >= n) return;
    int sub = (tid & 7) * 4;
    int j0 = row_ptr[row], j1 = row_ptr[row + 1];
    float ax = 0.f, ay = 0.f, az = 0.f, aw = 0.f;
    for (int j = j0; j < j1; ++j) {
        int2 p = pairs[j];                       // 8B broadcast load: (val, col)
        float v = __int_as_float(p.x);
        const float4 x = *reinterpret_cast<const float4*>(X + (long long)p.y * EMB + sub);
        ax = fmaf(v, x.x, ax);
        ay = fmaf(v, x.y, ay);
        az = fmaf(v, x.z, az);
        aw = fmaf(v, x.w, aw);
    }
    long long o = (long long)row * EMB + sub;
    if (STORE_E)
        *reinterpret_cast<float4*>(Eout + o) = make_float4(ax, ay, az, aw);
    float a = coefs[hop];
    if (INIT) {
        *reinterpret_cast<float4*>(Efin + o) = make_float4(a * ax, a * ay, a * az, a * aw);
    } else {
        float4 f = *reinterpret_cast<const float4*>(Efin + o);
        f.x += a * ax; f.y += a * ay; f.z += a * az; f.w += a * aw;
        *reinterpret_cast<float4*>(Efin + o) = f;
    }
}

// ---------------- atomic fallback (if ws too small for CSR) ----------------

__global__ void spmm_atomic_kernel(const float* __restrict__ vals, const int* __restrict__ rows,
                                   const int* __restrict__ cols, int nnz,
                                   const float* __restrict__ X, float* __restrict__ Eout) {
    long long stride = (long long)gridDim.x * blockDim.x;
    long long total = (long long)nnz * 8;
    for (long long t = (long long)blockIdx.x * blockDim.x + threadIdx.x; t < total; t += stride) {
        int i = (int)(t >> 3);
        int sub = ((int)t & 7) * 4;
        float v = vals[i];
        const float4 x = *reinterpret_cast<const float4*>(X + (long long)cols[i] * EMB + sub);
        float* o = Eout + (long long)rows[i] * EMB + sub;
        atomicAdd(o + 0, v * x.x);
        atomicAdd(o + 1, v * x.y);
        atomicAdd(o + 2, v * x.z);
        atomicAdd(o + 3, v * x.w);
    }
}

template <bool INIT>
__global__ void axpy_kernel(const float* __restrict__ E, float* __restrict__ Efin,
                            const float* __restrict__ coefs, int hop, int total4) {
    int i = blockIdx.x * blockDim.x + threadIdx.x;
    if (i >= total4) return;
    float a = coefs[hop];
    float4 e = reinterpret_cast<const float4*>(E)[i];
    if (INIT) {
        reinterpret_cast<float4*>(Efin)[i] = make_float4(a * e.x, a * e.y, a * e.z, a * e.w);
    } else {
        float4 f = reinterpret_cast<float4*>(Efin)[i];
        f.x += a * e.x; f.y += a * e.y; f.z += a * e.z; f.w += a * e.w;
        reinterpret_cast<float4*>(Efin)[i] = f;
    }
}

// ---------------- launch ----------------

extern "C" void kernel_launch(void* const* d_in, const int* in_sizes, int n_in,
                              void* d_out, int out_size, void* d_ws, size_t ws_size,
                              hipStream_t stream) {
    const float* A_vals = (const float*)d_in[0];
    const float* W0     = (const float*)d_in[1];
    const float* alpha  = (const float*)d_in[2];
    const int*   A_rows = (const int*)d_in[3];
    const int*   A_cols = (const int*)d_in[4];
    const int nnz = in_sizes[0];
    const int n   = in_sizes[1] / EMB;
    float* Efin = (float*)d_out;

    char* ws = (char*)d_ws;
    size_t off = 0;
    auto alloc = [&](size_t bytes) -> void* {
        void* p = (void*)(ws + off);
        off += (bytes + 255) & ~(size_t)255;
        return p;
    };

    // atomic-path allocations first, CSR extras after
    float* Ebuf0 = (float*)alloc((size_t)n * EMB * 4);
    float* Ebuf1 = (float*)alloc((size_t)n * EMB * 4);
    float* coefs = (float*)alloc(4 * sizeof(float));
    size_t off_atomic = off;
    (void)off_atomic;
    int*  cnt     = (int*)alloc((size_t)n * 4);
    int*  row_ptr = (int*)alloc((size_t)(n + 1) * 4);
    int*  blksum  = (int*)alloc(256 * 4);
    int2* pairs   = (int2*)alloc((size_t)nnz * 8);
    size_t off_csr = off;

    const int nblk = (n + SCAN_CHUNK - 1) / SCAN_CHUNK;
    const bool use_csr = (ws_size >= off_csr) && (nblk <= 256);

    softmax4_kernel<<<1, 64, 0, stream>>>(alpha, coefs);

    if (use_csr) {
        hipMemsetAsync(cnt, 0, (size_t)n * 4, stream);
        hist_kernel<<<2048, 256, 0, stream>>>(A_rows, nnz, cnt);
        scan_block_kernel<<<nblk, 256, 0, stream>>>(cnt, n, blksum);
        scan_tops_kernel<<<1, 256, 0, stream>>>(blksum, nblk);
        scan_add_kernel<<<(n + 1 + 255) / 256, 256, 0, stream>>>(cnt, blksum, n, nnz, row_ptr);
        scatter_kernel<<<2048, 256, 0, stream>>>(A_vals, A_rows, A_cols, nnz, cnt, pairs);

        int blocks = (n * 8 + 255) / 256;
        spmm_kernel<true,  true ><<<blocks, 256, 0, stream>>>(row_ptr, pairs, W0,    Ebuf0, Efin, coefs, 0, n);
        spmm_kernel<false, true ><<<blocks, 256, 0, stream>>>(row_ptr, pairs, Ebuf0, Ebuf1, Efin, coefs, 1, n);
        spmm_kernel<false, true ><<<blocks, 256, 0, stream>>>(row_ptr, pairs, Ebuf1, Ebuf0, Efin, coefs, 2, n);
        spmm_kernel<false, false><<<blocks, 256, 0, stream>>>(row_ptr, pairs, Ebuf0, Ebuf1, Efin, coefs, 3, n);
    } else {
        const float* X = W0;
        float* bufs[2] = {Ebuf0, Ebuf1};
        int total4 = n * EMB / 4;
        int ablocks = (total4 + 255) / 256;
        for (int hop = 0; hop < 4; ++hop) {
            float* Eo = bufs[hop & 1];
            hipMemsetAsync(Eo, 0, (size_t)n * EMB * 4, stream);
            spmm_atomic_kernel<<<2048, 256, 0, stream>>>(A_vals, A_rows, A_cols, nnz, X, Eo);
            if (hop == 0)
                axpy_kernel<true ><<<ablocks, 256, 0, stream>>>(Eo, Efin, coefs, hop, total4);
            else
                axpy_kernel<false><<<ablocks, 256, 0, stream>>>(Eo, Efin, coefs, hop, total4);
            X = Eo;
        }
    }
}

// Round 2
// 506.830 us; speedup vs baseline: 1.5638x; 1.5638x over previous
//
#include <hip/hip_runtime.h>

#define EMB 32
#define BSHIFT 10
#define ROWS_PER_BUCKET 1024   // 1 << BSHIFT
#define TILE 4096
#define PT_THREADS 256
#define PT_ITEMS 16            // TILE / PT_THREADS
#define SP_THREADS 1024

// ---------------- CSR build: two-phase counting sort ----------------

// A1: global bucket histogram (bucket = row >> BSHIFT), LDS-aggregated.
__global__ void bucket_hist_kernel(const int* __restrict__ rows, int nnz,
                                   int* __restrict__ bhist, int nb) {
    __shared__ int h[256];
    int t = threadIdx.x;
    h[t] = 0;
    __syncthreads();
    int stride = gridDim.x * blockDim.x;
    for (int i = blockIdx.x * blockDim.x + t; i < nnz; i += stride)
        atomicAdd(&h[rows[i] >> BSHIFT], 1);
    __syncthreads();
    if (t < nb && h[t] > 0) atomicAdd(&bhist[t], h[t]);
}

// A2: exclusive scan of bucket hist (nb <= 256) -> base[0..nb], cursor init.
__global__ void bucket_scan_kernel(const int* __restrict__ bhist, int nb, int nnz,
                                   int* __restrict__ base, int* __restrict__ cursor) {
    __shared__ int lds[256];
    int t = threadIdx.x;
    int s = (t < nb) ? bhist[t] : 0;
    lds[t] = s;
    __syncthreads();
    for (int off = 1; off < 256; off <<= 1) {
        int add = (t >= off) ? lds[t - off] : 0;
        __syncthreads();
        lds[t] += add;
        __syncthreads();
    }
    if (t < nb) {
        int e = lds[t] - s;
        base[t] = e;
        cursor[t] = e;
    }
    if (t == 0) base[nb] = nnz;
}

// A3: tile-wise partition into buckets with LDS reorder -> coalesced writes.
__global__ __launch_bounds__(PT_THREADS) void partition_kernel(
        const float* __restrict__ vals, const int* __restrict__ rows,
        const int* __restrict__ cols, int nnz, int* __restrict__ cursor,
        int2* __restrict__ pairs_stage, int* __restrict__ rows_stage) {
    __shared__ int h[256], sc[256], delta[256], cur[256];
    __shared__ float s_val[TILE];
    __shared__ int s_col[TILE], s_row[TILE];
    const int t = threadIdx.x;
    const int tile_start = blockIdx.x * TILE;
    const int tile_cnt = min(TILE, nnz - tile_start);
    h[t] = 0;
    __syncthreads();
    float v[PT_ITEMS];
    int c[PT_ITEMS], r[PT_ITEMS], b[PT_ITEMS];
    #pragma unroll
    for (int k = 0; k < PT_ITEMS; ++k) {
        int i = tile_start + t + k * PT_THREADS;
        if (i < nnz) {
            v[k] = vals[i];
            c[k] = cols[i];
            r[k] = rows[i];
            b[k] = r[k] >> BSHIFT;
            atomicAdd(&h[b[k]], 1);
        } else {
            b[k] = -1;
        }
    }
    __syncthreads();
    int own = h[t];
    sc[t] = own;
    __syncthreads();
    for (int off = 1; off < 256; off <<= 1) {
        int add = (t >= off) ? sc[t - off] : 0;
        __syncthreads();
        sc[t] += add;
        __syncthreads();
    }
    int excl = sc[t] - own;
    if (own > 0) {
        int rsv = atomicAdd(&cursor[t], own);   // reserve global range for bucket t
        delta[t] = rsv - excl;
    }
    cur[t] = excl;
    __syncthreads();
    // LDS reorder: scatter items into bucket-sorted order
    #pragma unroll
    for (int k = 0; k < PT_ITEMS; ++k) {
        if (b[k] >= 0) {
            int rank = atomicAdd(&cur[b[k]], 1);
            s_val[rank] = v[k];
            s_col[rank] = c[k];
            s_row[rank] = r[k];
        }
    }
    __syncthreads();
    // coalesced copy-out: consecutive sorted items -> consecutive global slots
    for (int i = t; i < tile_cnt; i += PT_THREADS) {
        int rw = s_row[i];
        int bb = rw >> BSHIFT;
        int gpos = delta[bb] + i;
        pairs_stage[gpos] = make_int2(__float_as_int(s_val[i]), s_col[i]);
        rows_stage[gpos] = rw;
    }
}

// B: per-bucket counting sort -> row_ptr + final CSR pairs.
// Scatter region per bucket ~131KB -> L2-resident, no HBM write amplification.
__global__ __launch_bounds__(SP_THREADS) void bucket_sort_kernel(
        const int2* __restrict__ pairs_stage, const int* __restrict__ rows_stage,
        const int* __restrict__ base, int n, int nnz,
        int* __restrict__ row_ptr, int2* __restrict__ pairs) {
    __shared__ int rh[ROWS_PER_BUCKET];
    __shared__ int rc[ROWS_PER_BUCKET];
    const int bkt = blockIdx.x;
    const int t = threadIdx.x;
    const int row0 = bkt << BSHIFT;
    const int nrows = min(ROWS_PER_BUCKET, n - row0);
    const int i0 = base[bkt], i1 = base[bkt + 1];
    rh[t] = 0;
    __syncthreads();
    for (int i = i0 + t; i < i1; i += SP_THREADS)
        atomicAdd(&rh[rows_stage[i] - row0], 1);
    __syncthreads();
    int own = rh[t];
    for (int off = 1; off < SP_THREADS; off <<= 1) {
        int add = (t >= off) ? rh[t - off] : 0;
        __syncthreads();
        rh[t] += add;
        __syncthreads();
    }
    int excl = rh[t] - own;
    if (t < nrows) row_ptr[row0 + t] = i0 + excl;
    rc[t] = excl;
    if (bkt == 0 && t == 0) row_ptr[n] = nnz;
    __syncthreads();
    for (int i = i0 + t; i < i1; i += SP_THREADS) {
        int2 p = pairs_stage[i];
        int r = rows_stage[i] - row0;
        int pos = i0 + atomicAdd(&rc[r], 1);
        pairs[pos] = p;
    }
}

// ---------------- misc ----------------

__global__ void softmax4_kernel(const float* __restrict__ alpha, float* __restrict__ coefs) {
    if (threadIdx.x == 0 && blockIdx.x == 0) {
        float m = fmaxf(fmaxf(alpha[0], alpha[1]), fmaxf(alpha[2], alpha[3]));
        float e0 = __expf(alpha[0] - m), e1 = __expf(alpha[1] - m);
        float e2 = __expf(alpha[2] - m), e3 = __expf(alpha[3] - m);
        float inv = 1.0f / (e0 + e1 + e2 + e3);
        coefs[0] = e0 * inv; coefs[1] = e1 * inv; coefs[2] = e2 * inv; coefs[3] = e3 * inv;
    }
}

// ---------------- CSR SpMM with fused weighted accumulation ----------------
// 8 lanes per row, float4 of EMB per lane. No atomics.

template <bool INIT, bool STORE_E>
__global__ void spmm_kernel(const int* __restrict__ row_ptr, const int2* __restrict__ pairs,
                            const float* __restrict__ X, float* __restrict__ Eout,
                            float* __restrict__ Efin, const float* __restrict__ coefs,
                            int hop, int n) {
    int tid = blockIdx.x * blockDim.x + threadIdx.x;
    int row = tid >> 3;
    if (row >= n) return;
    int sub = (tid & 7) * 4;
    int j0 = row_ptr[row], j1 = row_ptr[row + 1];
    float ax = 0.f, ay = 0.f, az = 0.f, aw = 0.f;
    for (int j = j0; j < j1; ++j) {
        int2 p = pairs[j];                       // 8B broadcast load: (val, col)
        float v = __int_as_float(p.x);
        const float4 x = *reinterpret_cast<const float4*>(X + (long long)p.y * EMB + sub);
        ax = fmaf(v, x.x, ax);
        ay = fmaf(v, x.y, ay);
        az = fmaf(v, x.z, az);
        aw = fmaf(v, x.w, aw);
    }
    long long o = (long long)row * EMB + sub;
    if (STORE_E)
        *reinterpret_cast<float4*>(Eout + o) = make_float4(ax, ay, az, aw);
    float a = coefs[hop];
    if (INIT) {
        *reinterpret_cast<float4*>(Efin + o) = make_float4(a * ax, a * ay, a * az, a * aw);
    } else {
        float4 f = *reinterpret_cast<const float4*>(Efin + o);
        f.x += a * ax; f.y += a * ay; f.z += a * az; f.w += a * aw;
        *reinterpret_cast<float4*>(Efin + o) = f;
    }
}

// ---------------- atomic fallback (if ws too small for CSR) ----------------

__global__ void spmm_atomic_kernel(const float* __restrict__ vals, const int* __restrict__ rows,
                                   const int* __restrict__ cols, int nnz,
                                   const float* __restrict__ X, float* __restrict__ Eout) {
    long long stride = (long long)gridDim.x * blockDim.x;
    long long total = (long long)nnz * 8;
    for (long long t = (long long)blockIdx.x * blockDim.x + threadIdx.x; t < total; t += stride) {
        int i = (int)(t >> 3);
        int sub = ((int)t & 7) * 4;
        float v = vals[i];
        const float4 x = *reinterpret_cast<const float4*>(X + (long long)cols[i] * EMB + sub);
        float* o = Eout + (long long)rows[i] * EMB + sub;
        atomicAdd(o + 0, v * x.x);
        atomicAdd(o + 1, v * x.y);
        atomicAdd(o + 2, v * x.z);
        atomicAdd(o + 3, v * x.w);
    }
}

template <bool INIT>
__global__ void axpy_kernel(const float* __restrict__ E, float* __restrict__ Efin,
                            const float* __restrict__ coefs, int hop, int total4) {
    int i = blockIdx.x * blockDim.x + threadIdx.x;
    if (i >= total4) return;
    float a = coefs[hop];
    float4 e = reinterpret_cast<const float4*>(E)[i];
    if (INIT) {
        reinterpret_cast<float4*>(Efin)[i] = make_float4(a * e.x, a * e.y, a * e.z, a * e.w);
    } else {
        float4 f = reinterpret_cast<float4*>(Efin)[i];
        f.x += a * e.x; f.y += a * e.y; f.z += a * e.z; f.w += a * e.w;
        reinterpret_cast<float4*>(Efin)[i] = f;
    }
}

// ---------------- launch ----------------

extern "C" void kernel_launch(void* const* d_in, const int* in_sizes, int n_in,
                              void* d_out, int out_size, void* d_ws, size_t ws_size,
                              hipStream_t stream) {
    const float* A_vals = (const float*)d_in[0];
    const float* W0     = (const float*)d_in[1];
    const float* alpha  = (const float*)d_in[2];
    const int*   A_rows = (const int*)d_in[3];
    const int*   A_cols = (const int*)d_in[4];
    const int nnz = in_sizes[0];
    const int n   = in_sizes[1] / EMB;
    float* Efin = (float*)d_out;

    char* ws = (char*)d_ws;
    size_t off = 0;
    auto alloc = [&](size_t bytes) -> void* {
        void* p = (void*)(ws + off);
        off += (bytes + 255) & ~(size_t)255;
        return p;
    };

    float* Ebuf0 = (float*)alloc((size_t)n * EMB * 4);
    float* Ebuf1 = (float*)alloc((size_t)n * EMB * 4);
    float* coefs = (float*)alloc(4 * sizeof(float));
    int*  row_ptr = (int*)alloc((size_t)(n + 1) * 4);
    int*  bhist   = (int*)alloc(256 * 4);
    int*  base    = (int*)alloc(257 * 4);
    int*  cursor  = (int*)alloc(256 * 4);
    int2* pairs   = (int2*)alloc((size_t)nnz * 8);
    size_t off_csr = off;

    // staging aliases Ebuf0/Ebuf1 (only live during CSR build, before spmm)
    int2* pairs_stage = (int2*)Ebuf0;   // nnz*8 bytes
    int*  rows_stage  = (int*)Ebuf1;    // nnz*4 bytes

    const int nb = (n + ROWS_PER_BUCKET - 1) >> BSHIFT;
    const bool use_csr = (ws_size >= off_csr) && (nb <= 256) &&
                         ((size_t)nnz * 8 <= (size_t)n * EMB * 4);

    softmax4_kernel<<<1, 64, 0, stream>>>(alpha, coefs);

    if (use_csr) {
        hipMemsetAsync(bhist, 0, 256 * 4, stream);
        bucket_hist_kernel<<<1024, 256, 0, stream>>>(A_rows, nnz, bhist, nb);
        bucket_scan_kernel<<<1, 256, 0, stream>>>(bhist, nb, nnz, base, cursor);
        partition_kernel<<<(nnz + TILE - 1) / TILE, PT_THREADS, 0, stream>>>(
            A_vals, A_rows, A_cols, nnz, cursor, pairs_stage, rows_stage);
        bucket_sort_kernel<<<nb, SP_THREADS, 0, stream>>>(
            pairs_stage, rows_stage, base, n, nnz, row_ptr, pairs);

        int blocks = (n * 8 + 255) / 256;
        spmm_kernel<true,  true ><<<blocks, 256, 0, stream>>>(row_ptr, pairs, W0,    Ebuf0, Efin, coefs, 0, n);
        spmm_kernel<false, true ><<<blocks, 256, 0, stream>>>(row_ptr, pairs, Ebuf0, Ebuf1, Efin, coefs, 1, n);
        spmm_kernel<false, true ><<<blocks, 256, 0, stream>>>(row_ptr, pairs, Ebuf1, Ebuf0, Efin, coefs, 2, n);
        spmm_kernel<false, false><<<blocks, 256, 0, stream>>>(row_ptr, pairs, Ebuf0, Ebuf1, Efin, coefs, 3, n);
    } else {
        const float* X = W0;
        float* bufs[2] = {Ebuf0, Ebuf1};
        int total4 = n * EMB / 4;
        int ablocks = (total4 + 255) / 256;
        for (int hop = 0; hop < 4; ++hop) {
            float* Eo = bufs[hop & 1];
            hipMemsetAsync(Eo, 0, (size_t)n * EMB * 4, stream);
            spmm_atomic_kernel<<<2048, 256, 0, stream>>>(A_vals, A_rows, A_cols, nnz, X, Eo);
            if (hop == 0)
                axpy_kernel<true ><<<ablocks, 256, 0, stream>>>(Eo, Efin, coefs, hop, total4);
            else
                axpy_kernel<false><<<ablocks, 256, 0, stream>>>(Eo, Efin, coefs, hop, total4);
            X = Eo;
        }
    }
}